// Round 15
// baseline (115.943 us; speedup 1.0000x reference)
//
#include <hip/hip_runtime.h>
#include <hip/hip_bf16.h>

typedef unsigned short u16;
typedef unsigned int u32;
typedef unsigned long long u64;
typedef __attribute__((ext_vector_type(8))) short short8;
typedef __attribute__((ext_vector_type(4))) short short4v;
typedef __attribute__((ext_vector_type(4))) float f32x4;

__device__ __forceinline__ u16 f2bf(float f) {
    union { float f; u32 u; } x; x.f = f;
    u32 r = x.u + 0x7fffu + ((x.u >> 16) & 1u);
    return (u16)(r >> 16);
}
__device__ __forceinline__ float fast_exp2(float x) {
#if __has_builtin(__builtin_amdgcn_exp2f)
    return __builtin_amdgcn_exp2f(x);
#else
    return exp2f(x);
#endif
}
// 16x16x16 bf16 MFMA (PV consumes P in-lane; k = kg*4+j matches QK^T output runs)
__device__ __forceinline__ f32x4 mfma16(short4v a, short4v b, f32x4 c) {
#if __has_builtin(__builtin_amdgcn_mfma_f32_16x16x16bf16_1k)
    return __builtin_amdgcn_mfma_f32_16x16x16bf16_1k(a, b, c, 0, 0, 0);
#else
    asm("v_mfma_f32_16x16x16_bf16 %0, %1, %2, %0" : "+v"(c) : "v"(a), "v"(b));
    return c;
#endif
}

#define AS1C const __attribute__((address_space(1))) void*
#define AS3  __attribute__((address_space(3))) void*

// ---------------------------------------------------------------------------
// pose embed GEMM: pe[b][j][t] = pose_embed[b][j][:] @ pose_W[:,t] + pose_b[t]
__global__ __launch_bounds__(256) void pe_kernel(
    const float* __restrict__ pose, const float* __restrict__ poseW,
    const float* __restrict__ poseB, float* __restrict__ out)
{
    __shared__ float pr[128];
    int bj = blockIdx.x, tid = threadIdx.x;
    if (tid < 128) pr[tid] = pose[bj * 128 + tid];
    __syncthreads();
#pragma unroll
    for (int r = 0; r < 4; ++r) {
        int t = r * 256 + tid;
        float acc = poseB[t];
        for (int p = 0; p < 128; ++p)
            acc += pr[p] * poseW[p * 1024 + t];
        out[bj * 1024 + t] = acc;
    }
}

// ---------------------------------------------------------------------------
// fused transpose + dual LayerNorm pack (f32 in, bf16 out):
//   xn [8192][512] bf16; xpn[8192][544] bf16 (cols 514..543 = 0)
__global__ __launch_bounds__(512) void lnpack_kernel(
    const float* __restrict__ x, const float* __restrict__ pe,
    const float* __restrict__ ng, const float* __restrict__ nb,
    const float* __restrict__ pg, const float* __restrict__ pb,
    u16* __restrict__ xn, u16* __restrict__ xpn)
{
    __shared__ float tile[512 * 33];   // [c][t], stride 33 (bank-conflict-free)
    __shared__ float red[2][32][17];
    __shared__ float stats[6][32];     // m1 r1 m2 r2 pe0 pe1
    int tid = threadIdx.x;
    int b = blockIdx.y, t0 = blockIdx.x * 32;
#pragma unroll
    for (int it = 0; it < 8; ++it) {
        int ch = it * 512 + tid;          // 0..4095
        int c = ch >> 3, tc = (ch & 7) * 4;
        const float* gp = x + ((size_t)b * 512 + c) * 1024 + t0 + tc;
        float4 v = *(const float4*)gp;
        float* rowp = tile + c * 33 + tc;
        rowp[0] = v.x; rowp[1] = v.y; rowp[2] = v.z; rowp[3] = v.w;
    }
    __syncthreads();
    {
        int tl = tid & 31, cg = tid >> 5;
        float s = 0.f, sq = 0.f;
        for (int i = 0; i < 32; ++i) {
            int c = cg * 32 + i;
            float v = tile[c * 33 + tl];
            s += v; sq += v * v;
        }
        red[0][tl][cg] = s; red[1][tl][cg] = sq;
    }
    __syncthreads();
    if (tid < 32) {
        float S = 0.f, Q = 0.f;
        for (int g = 0; g < 16; ++g) { S += red[0][tid][g]; Q += red[1][tid][g]; }
        float m1 = S * (1.f / 512.f);
        float v1 = fmaxf(Q * (1.f / 512.f) - m1 * m1, 0.f);
        float r1 = rsqrtf(v1 + 1e-5f);
        float p0 = pe[(size_t)b * 2048 + t0 + tid];
        float p1 = pe[(size_t)b * 2048 + 1024 + t0 + tid];
        float S2 = S + p0 + p1, Q2 = Q + p0 * p0 + p1 * p1;
        float m2 = S2 * (1.f / 514.f);
        float v2 = fmaxf(Q2 * (1.f / 514.f) - m2 * m2, 0.f);
        float r2 = rsqrtf(v2 + 1e-5f);
        stats[0][tid] = m1; stats[1][tid] = r1; stats[2][tid] = m2;
        stats[3][tid] = r2; stats[4][tid] = p0; stats[5][tid] = p1;
    }
    __syncthreads();
    {
        int c = tid;
        float g1 = ng[c], b1 = nb[c];
        float g2 = pg[c], b2 = pb[c];
        for (int t = 0; t < 32; ++t) {
            float v = tile[c * 33 + t];
            int T = t0 + t;
            xn [((size_t)b * 1024 + T) * 512 + c] = f2bf((v - stats[0][t]) * stats[1][t] * g1 + b1);
            xpn[((size_t)b * 1024 + T) * 544 + c] = f2bf((v - stats[2][t]) * stats[3][t] * g2 + b2);
        }
        if (tid < 32) {
            float gg = (tid < 2) ? pg[512 + tid] : 0.f;
            float bbv = (tid < 2) ? pb[512 + tid] : 0.f;
            for (int t = 0; t < 32; ++t) {
                float val = 0.f;
                if (tid < 2)
                    val = (stats[4 + tid][t] - stats[2][t]) * stats[3][t] * gg + bbv;
                xpn[((size_t)b * 1024 + (t0 + t)) * 544 + 512 + tid] = f2bf(val);
            }
        }
    }
}

// ---------------------------------------------------------------------------
// weight transpose [K][N] f32 -> [N][Kpad] bf16 (zero-padded rows beyond Kdim)
__global__ __launch_bounds__(256) void wtrans_kernel(
    const float* __restrict__ qW, const float* __restrict__ kW,
    const float* __restrict__ vW, const float* __restrict__ pW,
    u16* __restrict__ qWt, u16* __restrict__ kWt,
    u16* __restrict__ vWt, u16* __restrict__ pWt)
{
    int z = blockIdx.z;
    const float* src = (z == 0) ? qW : (z == 1) ? kW : (z == 2) ? vW : pW;
    u16* dst = (z == 0) ? qWt : (z == 1) ? kWt : (z == 2) ? vWt : pWt;
    int Kdim = (z == 1 || z == 2) ? 514 : 512;
    int Kpad = (z == 1 || z == 2) ? 544 : 512;
    int n0 = blockIdx.x * 32, k0 = blockIdx.y * 32;
    if (k0 >= Kpad) return;
    __shared__ float tt[32][33];
    int xx = threadIdx.x & 31, yy = threadIdx.x >> 5;
#pragma unroll
    for (int r = 0; r < 4; ++r) {
        int k = k0 + yy * 4 + r;
        tt[xx][yy * 4 + r] = (k < Kdim) ? src[(size_t)k * 512 + n0 + xx] : 0.f;
    }
    __syncthreads();
#pragma unroll
    for (int r = 0; r < 4; ++r) {
        int nl = yy * 4 + r;
        dst[(size_t)(n0 + nl) * Kpad + k0 + xx] = f2bf(tt[nl][xx]);
    }
}

// ---------------------------------------------------------------------------
// MFMA GEMM, tile 128x64, BK=64, DOUBLE-BUFFERED single-barrier loop
// (round-15: attn-proven 2-phase structure -- STAGE(next buf) issued before
// the compute phase, ONE __syncthreads per K-step drains prefetch + guards
// buffer reuse; staging latency hides under 16 MFMA + 12 ds_read).
// K=544 handled by a 32-wide tail staged into the ping-pong buffer.
// mode 0: qkv-scatter epilogue (reference's 192-channel head rule);
// mode 2: proj out f32, float4 store. bias: gcol<512?bias0:bias1 (kv merge).
#define BM 128
#define BN 64
#define QSCALE 0.18033688f   /* 0.125 * log2(e) */
__global__ __launch_bounds__(256) void gemm_kernel(
    const u16* __restrict__ A, int lda,
    const u16* __restrict__ Bt, int ldb,
    const float* __restrict__ bias0, const float* __restrict__ bias1,
    int K, int mode, int coff,
    u16* __restrict__ oq, u16* __restrict__ ok, u16* __restrict__ ov,
    float* __restrict__ out32)
{
    __shared__ __align__(16) u16 As[2][BM * 64];
    __shared__ __align__(16) u16 Bs[2][BN * 64];
    const int tid = threadIdx.x;
    const int lane = tid & 63, w = tid >> 6;
    const int row0 = blockIdx.x * BM, col0 = blockIdx.y * BN;
    const int woffM = (w & 1) * 64, woffN = (w >> 1) * 32;
    const int lr = lane & 15, kg = lane >> 4;
    const int nfull = K >> 6;              // 8 for K=512 and K=544
    const bool tail = (K & 63) != 0;       // K=544 -> 32-wide tail
    f32x4 acc[4][2] = {};

#define STAGE64(bf, kk) { \
    _Pragma("unroll") \
    for (int h = 0; h < 6; ++h) { \
        int c = tid + h * 256; \
        if (c < 1024) { \
            int r = c >> 3, sl = c & 7; \
            int kc2 = sl ^ (r & 7); \
            __builtin_amdgcn_global_load_lds( \
                (AS1C)(A + (size_t)(row0 + r) * lda + (kk) + kc2 * 8), \
                (AS3)(As[bf] + c * 8), 16, 0, 0); \
        } else { \
            int cB = c - 1024; \
            int r = cB >> 3, sl = cB & 7; \
            int kc2 = sl ^ (r & 7); \
            __builtin_amdgcn_global_load_lds( \
                (AS1C)(Bt + (size_t)(col0 + r) * ldb + (kk) + kc2 * 8), \
                (AS3)(Bs[bf] + cB * 8), 16, 0, 0); \
        } } }

#define STAGE32(bf, kk) { \
    _Pragma("unroll") \
    for (int h = 0; h < 3; ++h) { \
        int c = tid + h * 256; \
        if (c < 512) { \
            int r = c >> 2, sl = c & 3; \
            int kc2 = sl ^ (r & 3); \
            __builtin_amdgcn_global_load_lds( \
                (AS1C)(A + (size_t)(row0 + r) * lda + (kk) + kc2 * 8), \
                (AS3)(As[bf] + c * 8), 16, 0, 0); \
        } else { \
            int cB = c - 512; \
            int r = cB >> 2, sl = cB & 3; \
            int kc2 = sl ^ (r & 3); \
            __builtin_amdgcn_global_load_lds( \
                (AS1C)(Bt + (size_t)(col0 + r) * ldb + (kk) + kc2 * 8), \
                (AS3)(Bs[bf] + cB * 8), 16, 0, 0); \
        } } }

    STAGE64(0, 0)
    __syncthreads();
    int buf = 0;
    for (int step = 0; step < nfull; ++step) {
        int knext = (step + 1) << 6;
        if (step + 1 < nfull) { STAGE64(buf ^ 1, knext) }
        else if (tail)        { STAGE32(buf ^ 1, knext) }
        short8 af[4][2], bfr[2][2];
#pragma unroll
        for (int m = 0; m < 4; ++m) {
            int r = woffM + m * 16 + lr;
            const u16* base = As[buf] + r * 64;
            af[m][0] = *(const short8*)(base + ((kg ^ (r & 7)) * 8));
            af[m][1] = *(const short8*)(base + (((kg + 4) ^ (r & 7)) * 8));
        }
#pragma unroll
        for (int n = 0; n < 2; ++n) {
            int r = woffN + n * 16 + lr;
            const u16* base = Bs[buf] + r * 64;
            bfr[n][0] = *(const short8*)(base + ((kg ^ (r & 7)) * 8));
            bfr[n][1] = *(const short8*)(base + (((kg + 4) ^ (r & 7)) * 8));
        }
#pragma unroll
        for (int m = 0; m < 4; ++m)
#pragma unroll
            for (int n = 0; n < 2; ++n) {
                acc[m][n] = __builtin_amdgcn_mfma_f32_16x16x32_bf16(af[m][0], bfr[n][0], acc[m][n], 0, 0, 0);
                acc[m][n] = __builtin_amdgcn_mfma_f32_16x16x32_bf16(af[m][1], bfr[n][1], acc[m][n], 0, 0, 0);
            }
        __syncthreads();           // drains prefetch vmcnt + guards buffer reuse
        buf ^= 1;
    }
    if (tail) {   // 32-wide tail compute (staged into As[buf] by last step)
        short8 af[4], bfr[2];
#pragma unroll
        for (int m = 0; m < 4; ++m) {
            int r = woffM + m * 16 + lr;
            af[m] = *(const short8*)(As[buf] + r * 32 + ((kg ^ (r & 3)) * 8));
        }
#pragma unroll
        for (int n = 0; n < 2; ++n) {
            int r = woffN + n * 16 + lr;
            bfr[n] = *(const short8*)(Bs[buf] + r * 32 + ((kg ^ (r & 3)) * 8));
        }
#pragma unroll
        for (int m = 0; m < 4; ++m)
#pragma unroll
            for (int n = 0; n < 2; ++n)
                acc[m][n] = __builtin_amdgcn_mfma_f32_16x16x32_bf16(af[m], bfr[n], acc[m][n], 0, 0, 0);
    }
#undef STAGE64
#undef STAGE32
#pragma unroll
    for (int m = 0; m < 4; ++m) {
#pragma unroll
        for (int n = 0; n < 2; ++n) {
            int gcol = col0 + woffN + n * 16 + lr;
            float bv = (gcol < 512) ? bias0[gcol] : bias1[gcol - 512];
            int growb = row0 + woffM + m * 16 + kg * 4;   // j=0..3 contiguous
            int bb = growb >> 10, t0v = growb & 1023;
            float v0 = acc[m][n][0] + bv, v1 = acc[m][n][1] + bv;
            float v2 = acc[m][n][2] + bv, v3 = acc[m][n][3] + bv;
            if (mode == 0) {
                int cg = coff + gcol;
                int h = cg / 192;
                int rr = cg - h * 192;
                int role = rr >> 6, d = rr & 63;
                if (role == 0) { v0 *= QSCALE; v1 *= QSCALE; v2 *= QSCALE; v3 *= QSCALE; }
                if (role == 2) {
                    size_t base = ((((size_t)bb * 8 + h) * 64 + d) << 10) + t0v;
                    u64 pk = (u64)f2bf(v0) | ((u64)f2bf(v1) << 16)
                           | ((u64)f2bf(v2) << 32) | ((u64)f2bf(v3) << 48);
                    *(u64*)(ov + base) = pk;
                } else {
                    u16* o = role ? ok : oq;
                    size_t base = ((((size_t)bb * 8 + h) * 1024 + t0v) << 6) + d;
                    o[base]       = f2bf(v0);
                    o[base + 64]  = f2bf(v1);
                    o[base + 128] = f2bf(v2);
                    o[base + 192] = f2bf(v3);
                }
            } else {
                size_t base = (((size_t)bb * 512 + gcol) << 10) + t0v;
                float4 f4; f4.x = v0; f4.y = v1; f4.z = v2; f4.w = v3;
                *(float4*)(out32 + base) = f4;
            }
        }
    }
}

// ---------------------------------------------------------------------------
// flash attention, swapped-QK^T, no-max softmax (exact by shift-invariance).
// LDS-staged K/V via global_load_lds (round-10: 122 -> 44 us). Round-12 PV:
// 2x mfma_16x16x16 per st-block, P consumed in-lane (no ds_bpermute).
// 64 q-rows/block, 1024 blocks = 4 blocks/CU (round-13 taught: tile-up
// halves TLP and is net-negative).
__global__ __launch_bounds__(256, 1) void attn_kernel(
    const u16* __restrict__ qb, const u16* __restrict__ kb,
    const u16* __restrict__ vt, u16* __restrict__ ob)
{
    __shared__ __align__(16) u16 Kl[2][4096];   // [buf][64 rows x 8 chunks x 8 u16]
    __shared__ __align__(16) u16 Vl[2][4096];
    int tid = threadIdx.x, lane = tid & 63, w = tid >> 6;
    int bid = blockIdx.x;                       // 0..1023 flat
    int wid = (bid & 7) * 128 + (bid >> 3);     // XCD-contiguous work id
    int qt = wid & 15;
    int hh = (wid >> 4) & 7;
    int bbb = wid >> 7;
    int bh = bbb * 8 + hh;
    int q0 = qt * 64 + w * 16;
    int lr = lane & 15, kg = lane >> 4;
    const u16* qbase = qb + ((size_t)bh * 1024 + q0 + lr) * 64;
    short8 qf0 = *(const short8*)(qbase + kg * 8);
    short8 qf1 = *(const short8*)(qbase + 32 + kg * 8);
    f32x4 oT[4] = {};
    float lsum = 0.f;
    const u16* kbase = kb + (size_t)bh * 1024 * 64;
    const u16* vbase = vt + (size_t)bh * 64 * 1024;
    const int xr = lr & 7;
    const int vho = (kg & 1) * 4;     // within-chunk u16 offset for V b64 reads
    const int vkg2 = kg >> 1;

#define STAGE(bf, s0) { \
    int g0 = tid, g1 = tid + 256; \
    { int r = g0 >> 3, cl = g0 & 7, cg = cl ^ (r & 7); \
      __builtin_amdgcn_global_load_lds((AS1C)(kbase + (size_t)((s0) + r) * 64 + cg * 8), \
                                       (AS3)(&Kl[bf][g0 * 8]), 16, 0, 0); } \
    { int r = g1 >> 3, cl = g1 & 7, cg = cl ^ (r & 7); \
      __builtin_amdgcn_global_load_lds((AS1C)(kbase + (size_t)((s0) + r) * 64 + cg * 8), \
                                       (AS3)(&Kl[bf][g1 * 8]), 16, 0, 0); } \
    { int d = g0 >> 3, cl = g0 & 7, cg = cl ^ (d & 7); \
      __builtin_amdgcn_global_load_lds((AS1C)(vbase + (size_t)d * 1024 + (s0) + cg * 8), \
                                       (AS3)(&Vl[bf][g0 * 8]), 16, 0, 0); } \
    { int d = g1 >> 3, cl = g1 & 7, cg = cl ^ (d & 7); \
      __builtin_amdgcn_global_load_lds((AS1C)(vbase + (size_t)d * 1024 + (s0) + cg * 8), \
                                       (AS3)(&Vl[bf][g1 * 8]), 16, 0, 0); } }

#define BODY(bf, st2) { \
    const u16* Kb = &Kl[bf][0]; \
    const u16* Vb = &Vl[bf][0]; \
    int rA = ((st2) * 32 + lr) * 64, rB = ((st2) * 32 + 16 + lr) * 64; \
    short8 k00 = *(const short8*)(Kb + rA + ((kg ^ xr) * 8)); \
    short8 k01 = *(const short8*)(Kb + rA + (((kg + 4) ^ xr) * 8)); \
    short8 k10 = *(const short8*)(Kb + rB + ((kg ^ xr) * 8)); \
    short8 k11 = *(const short8*)(Kb + rB + (((kg + 4) ^ xr) * 8)); \
    f32x4 sc0 = {}, sc1 = {}; \
    sc0 = __builtin_amdgcn_mfma_f32_16x16x32_bf16(k00, qf0, sc0, 0, 0, 0); \
    sc0 = __builtin_amdgcn_mfma_f32_16x16x32_bf16(k01, qf1, sc0, 0, 0, 0); \
    sc1 = __builtin_amdgcn_mfma_f32_16x16x32_bf16(k10, qf0, sc1, 0, 0, 0); \
    sc1 = __builtin_amdgcn_mfma_f32_16x16x32_bf16(k11, qf1, sc1, 0, 0, 0); \
    float p0 = fast_exp2(sc0[0]), p1 = fast_exp2(sc0[1]); \
    float p2 = fast_exp2(sc0[2]), p3 = fast_exp2(sc0[3]); \
    float p4 = fast_exp2(sc1[0]), p5 = fast_exp2(sc1[1]); \
    float p6 = fast_exp2(sc1[2]), p7 = fast_exp2(sc1[3]); \
    lsum += (((p0 + p1) + (p2 + p3)) + ((p4 + p5) + (p6 + p7))); \
    short4v pb0, pb1; \
    pb0[0] = (short)f2bf(p0); pb0[1] = (short)f2bf(p1); \
    pb0[2] = (short)f2bf(p2); pb0[3] = (short)f2bf(p3); \
    pb1[0] = (short)f2bf(p4); pb1[1] = (short)f2bf(p5); \
    pb1[2] = (short)f2bf(p6); pb1[3] = (short)f2bf(p7); \
    int c0 = ((((st2) * 4 + vkg2) ^ xr) * 8) + vho; \
    int c1 = ((((st2) * 4 + 2 + vkg2) ^ xr) * 8) + vho; \
    short4v va; \
    va = *(const short4v*)(Vb + (lr) * 64 + c0);       oT[0] = mfma16(va, pb0, oT[0]); \
    va = *(const short4v*)(Vb + (lr) * 64 + c1);       oT[0] = mfma16(va, pb1, oT[0]); \
    va = *(const short4v*)(Vb + (16 + lr) * 64 + c0);  oT[1] = mfma16(va, pb0, oT[1]); \
    va = *(const short4v*)(Vb + (16 + lr) * 64 + c1);  oT[1] = mfma16(va, pb1, oT[1]); \
    va = *(const short4v*)(Vb + (32 + lr) * 64 + c0);  oT[2] = mfma16(va, pb0, oT[2]); \
    va = *(const short4v*)(Vb + (32 + lr) * 64 + c1);  oT[2] = mfma16(va, pb1, oT[2]); \
    va = *(const short4v*)(Vb + (48 + lr) * 64 + c0);  oT[3] = mfma16(va, pb0, oT[3]); \
    va = *(const short4v*)(Vb + (48 + lr) * 64 + c1);  oT[3] = mfma16(va, pb1, oT[3]); }

    STAGE(0, 0)
    __syncthreads();               // barrier drains vmcnt -> buf0 ready
    for (int step = 0; step < 16; ++step) {
        int cur = step & 1;
        if (step < 15) STAGE(cur ^ 1, (step + 1) * 64)   // prefetch next tile
        BODY(cur, 0)
        BODY(cur, 1)
        __syncthreads();           // drains prefetch vmcnt + guards reuse
    }
#undef STAGE
#undef BODY

    float Z = lsum;
    Z += __shfl_xor(Z, 16);
    Z += __shfl_xor(Z, 32);
    float inv = 1.f / Z;
    u16* obase = ob + ((size_t)bbb * 1024 + q0 + lr) * 512 + hh * 64;
#pragma unroll
    for (int dt = 0; dt < 4; ++dt) {
        u32 lo = ((u32)f2bf(oT[dt][0] * inv)) | (((u32)f2bf(oT[dt][1] * inv)) << 16);
        u32 hi = ((u32)f2bf(oT[dt][2] * inv)) | (((u32)f2bf(oT[dt][3] * inv)) << 16);
        u32* dstp = (u32*)(obase + dt * 16 + kg * 4);
        dstp[0] = lo; dstp[1] = hi;
    }
}

// ---------------------------------------------------------------------------
extern "C" void kernel_launch(void* const* d_in, const int* in_sizes, int n_in,
                              void* d_out, int out_size, void* d_ws, size_t ws_size,
                              hipStream_t stream)
{
    (void)in_sizes; (void)n_in; (void)out_size;
    const float* x       = (const float*)d_in[0];
    const float* pose    = (const float*)d_in[1];
    const float* norm_g  = (const float*)d_in[2];
    const float* norm_b  = (const float*)d_in[3];
    const float* pnorm_g = (const float*)d_in[4];
    const float* pnorm_b = (const float*)d_in[5];
    const float* pose_W  = (const float*)d_in[6];
    const float* pose_b  = (const float*)d_in[7];
    const float* q_W     = (const float*)d_in[8];
    const float* q_b     = (const float*)d_in[9];
    const float* k_W     = (const float*)d_in[10];
    const float* k_b     = (const float*)d_in[11];
    const float* v_W     = (const float*)d_in[12];
    const float* v_b     = (const float*)d_in[13];
    const float* proj_W  = (const float*)d_in[14];
    const float* proj_b  = (const float*)d_in[15];
    float* out = (float*)d_out;

    if (ws_size < 44695552u) return;

    char* ws = (char*)d_ws;
    float* pe_ws = (float*)(ws);                       // 65,536 B
    u16* xn    = (u16*)(ws + 65536);                   // 8,388,608 (reused as obuf)
    u16* xpn   = (u16*)(ws + 8454144);                 // 8,912,896
    u16* qWt   = (u16*)(ws + 17367040);                // 524,288
    u16* kWt   = (u16*)(ws + 17891328);                // 557,056  (kv merged:
    u16* vWt   = (u16*)(ws + 18448384);                //  vWt adjacent to kWt)
    u16* pWt   = (u16*)(ws + 19005440);                // 524,288
    u16* qbuf  = (u16*)(ws + 19529728);                // 8,388,608
    u16* kbuf  = (u16*)(ws + 27918336);                // 8,388,608
    u16* vtb   = (u16*)(ws + 36306944);                // 8,388,608
    u16* obuf  = xn;  // xn dead after q-gemm; attn writes obuf afterwards

    hipLaunchKernelGGL(wtrans_kernel, dim3(16, 17, 4), dim3(256), 0, stream,
                       q_W, k_W, v_W, proj_W, qWt, kWt, vWt, pWt);
    hipLaunchKernelGGL(pe_kernel, dim3(16), dim3(256), 0, stream,
                       pose, pose_W, pose_b, pe_ws);
    hipLaunchKernelGGL(lnpack_kernel, dim3(32, 8), dim3(512), 0, stream,
                       x, pe_ws, norm_g, norm_b, pnorm_g, pnorm_b, xn, xpn);
    // q projection (concat channels 0..511)
    hipLaunchKernelGGL(gemm_kernel, dim3(64, 8), dim3(256), 0, stream,
                       xn, 512, qWt, 512, q_b, q_b, 512, 0, 0,
                       qbuf, kbuf, vtb, (float*)nullptr);
    // merged k+v projection (concat channels 512..1535; kWt/vWt adjacent)
    hipLaunchKernelGGL(gemm_kernel, dim3(64, 16), dim3(256), 0, stream,
                       xpn, 544, kWt, 544, k_b, v_b, 544, 0, 512,
                       qbuf, kbuf, vtb, (float*)nullptr);
    hipLaunchKernelGGL(attn_kernel, dim3(1024), dim3(256), 0, stream,
                       qbuf, kbuf, vtb, obuf);
    hipLaunchKernelGGL(gemm_kernel, dim3(64, 8), dim3(256), 0, stream,
                       obuf, 512, pWt, 512, proj_b, proj_b, 512, 2, 0,
                       (u16*)nullptr, (u16*)nullptr, (u16*)nullptr, out);
}

// Round 16
// 111.029 us; speedup vs baseline: 1.0443x; 1.0443x over previous
//
#include <hip/hip_runtime.h>
#include <hip/hip_bf16.h>

typedef unsigned short u16;
typedef unsigned int u32;
typedef unsigned long long u64;
typedef __attribute__((ext_vector_type(8))) short short8;
typedef __attribute__((ext_vector_type(4))) short short4v;
typedef __attribute__((ext_vector_type(4))) float f32x4;

__device__ __forceinline__ u16 f2bf(float f) {
    union { float f; u32 u; } x; x.f = f;
    u32 r = x.u + 0x7fffu + ((x.u >> 16) & 1u);
    return (u16)(r >> 16);
}
// HW bf16 cast pair-pack (RNE; compiler may fuse to v_cvt_pk_bf16_f32 per m240)
__device__ __forceinline__ u32 pkbf(float a, float b) {
    union { __hip_bfloat16 h; u16 u; } xa, xb;
    xa.h = __float2bfloat16(a);
    xb.h = __float2bfloat16(b);
    return (u32)xa.u | ((u32)xb.u << 16);
}
__device__ __forceinline__ float fast_exp2(float x) {
#if __has_builtin(__builtin_amdgcn_exp2f)
    return __builtin_amdgcn_exp2f(x);
#else
    return exp2f(x);
#endif
}
// 16x16x16 bf16 MFMA (PV consumes P in-lane; k = kg*4+j matches QK^T output runs)
__device__ __forceinline__ f32x4 mfma16(short4v a, short4v b, f32x4 c) {
#if __has_builtin(__builtin_amdgcn_mfma_f32_16x16x16bf16_1k)
    return __builtin_amdgcn_mfma_f32_16x16x16bf16_1k(a, b, c, 0, 0, 0);
#else
    asm("v_mfma_f32_16x16x16_bf16 %0, %1, %2, %0" : "+v"(c) : "v"(a), "v"(b));
    return c;
#endif
}

#define AS1C const __attribute__((address_space(1))) void*
#define AS3  __attribute__((address_space(3))) void*

// ---------------------------------------------------------------------------
// pose embed GEMM: pe[b][j][t] = pose_embed[b][j][:] @ pose_W[:,t] + pose_b[t]
__global__ __launch_bounds__(256) void pe_kernel(
    const float* __restrict__ pose, const float* __restrict__ poseW,
    const float* __restrict__ poseB, float* __restrict__ out)
{
    __shared__ float pr[128];
    int bj = blockIdx.x, tid = threadIdx.x;
    if (tid < 128) pr[tid] = pose[bj * 128 + tid];
    __syncthreads();
#pragma unroll
    for (int r = 0; r < 4; ++r) {
        int t = r * 256 + tid;
        float acc = poseB[t];
        for (int p = 0; p < 128; ++p)
            acc += pr[p] * poseW[p * 1024 + t];
        out[bj * 1024 + t] = acc;
    }
}

// ---------------------------------------------------------------------------
// fused transpose + dual LayerNorm pack (f32 in, bf16 out):
//   xn [8192][512] bf16; xpn[8192][544] bf16 (cols 514..543 = 0)
__global__ __launch_bounds__(512) void lnpack_kernel(
    const float* __restrict__ x, const float* __restrict__ pe,
    const float* __restrict__ ng, const float* __restrict__ nb,
    const float* __restrict__ pg, const float* __restrict__ pb,
    u16* __restrict__ xn, u16* __restrict__ xpn)
{
    __shared__ float tile[512 * 33];   // [c][t], stride 33 (bank-conflict-free)
    __shared__ float red[2][32][17];
    __shared__ float stats[6][32];     // m1 r1 m2 r2 pe0 pe1
    int tid = threadIdx.x;
    int b = blockIdx.y, t0 = blockIdx.x * 32;
#pragma unroll
    for (int it = 0; it < 8; ++it) {
        int ch = it * 512 + tid;          // 0..4095
        int c = ch >> 3, tc = (ch & 7) * 4;
        const float* gp = x + ((size_t)b * 512 + c) * 1024 + t0 + tc;
        float4 v = *(const float4*)gp;
        float* rowp = tile + c * 33 + tc;
        rowp[0] = v.x; rowp[1] = v.y; rowp[2] = v.z; rowp[3] = v.w;
    }
    __syncthreads();
    {
        int tl = tid & 31, cg = tid >> 5;
        float s = 0.f, sq = 0.f;
        for (int i = 0; i < 32; ++i) {
            int c = cg * 32 + i;
            float v = tile[c * 33 + tl];
            s += v; sq += v * v;
        }
        red[0][tl][cg] = s; red[1][tl][cg] = sq;
    }
    __syncthreads();
    if (tid < 32) {
        float S = 0.f, Q = 0.f;
        for (int g = 0; g < 16; ++g) { S += red[0][tid][g]; Q += red[1][tid][g]; }
        float m1 = S * (1.f / 512.f);
        float v1 = fmaxf(Q * (1.f / 512.f) - m1 * m1, 0.f);
        float r1 = rsqrtf(v1 + 1e-5f);
        float p0 = pe[(size_t)b * 2048 + t0 + tid];
        float p1 = pe[(size_t)b * 2048 + 1024 + t0 + tid];
        float S2 = S + p0 + p1, Q2 = Q + p0 * p0 + p1 * p1;
        float m2 = S2 * (1.f / 514.f);
        float v2 = fmaxf(Q2 * (1.f / 514.f) - m2 * m2, 0.f);
        float r2 = rsqrtf(v2 + 1e-5f);
        stats[0][tid] = m1; stats[1][tid] = r1; stats[2][tid] = m2;
        stats[3][tid] = r2; stats[4][tid] = p0; stats[5][tid] = p1;
    }
    __syncthreads();
    {
        int c = tid;
        float g1 = ng[c], b1 = nb[c];
        float g2 = pg[c], b2 = pb[c];
        for (int t = 0; t < 32; ++t) {
            float v = tile[c * 33 + t];
            int T = t0 + t;
            xn [((size_t)b * 1024 + T) * 512 + c] = f2bf((v - stats[0][t]) * stats[1][t] * g1 + b1);
            xpn[((size_t)b * 1024 + T) * 544 + c] = f2bf((v - stats[2][t]) * stats[3][t] * g2 + b2);
        }
        if (tid < 32) {
            float gg = (tid < 2) ? pg[512 + tid] : 0.f;
            float bbv = (tid < 2) ? pb[512 + tid] : 0.f;
            for (int t = 0; t < 32; ++t) {
                float val = 0.f;
                if (tid < 2)
                    val = (stats[4 + tid][t] - stats[2][t]) * stats[3][t] * gg + bbv;
                xpn[((size_t)b * 1024 + (t0 + t)) * 544 + 512 + tid] = f2bf(val);
            }
        }
    }
}

// ---------------------------------------------------------------------------
// weight transpose [K][N] f32 -> [N][Kpad] bf16 (zero-padded rows beyond Kdim)
__global__ __launch_bounds__(256) void wtrans_kernel(
    const float* __restrict__ qW, const float* __restrict__ kW,
    const float* __restrict__ vW, const float* __restrict__ pW,
    u16* __restrict__ qWt, u16* __restrict__ kWt,
    u16* __restrict__ vWt, u16* __restrict__ pWt)
{
    int z = blockIdx.z;
    const float* src = (z == 0) ? qW : (z == 1) ? kW : (z == 2) ? vW : pW;
    u16* dst = (z == 0) ? qWt : (z == 1) ? kWt : (z == 2) ? vWt : pWt;
    int Kdim = (z == 1 || z == 2) ? 514 : 512;
    int Kpad = (z == 1 || z == 2) ? 544 : 512;
    int n0 = blockIdx.x * 32, k0 = blockIdx.y * 32;
    if (k0 >= Kpad) return;
    __shared__ float tt[32][33];
    int xx = threadIdx.x & 31, yy = threadIdx.x >> 5;
#pragma unroll
    for (int r = 0; r < 4; ++r) {
        int k = k0 + yy * 4 + r;
        tt[xx][yy * 4 + r] = (k < Kdim) ? src[(size_t)k * 512 + n0 + xx] : 0.f;
    }
    __syncthreads();
#pragma unroll
    for (int r = 0; r < 4; ++r) {
        int nl = yy * 4 + r;
        dst[(size_t)(n0 + nl) * Kpad + k0 + xx] = f2bf(tt[nl][xx]);
    }
}

// ---------------------------------------------------------------------------
// MFMA GEMM (round-14 winner, verbatim): tile 128x64, BK=64 main steps +
// optional 32-wide tail (K=544). 2-barrier single-buffer, 24KB LDS -> 6
// blocks/CU; round-15 taught: dbuf at 48KB halves occupancy and loses (TLP
// is the latency-hiding mechanism here, not intra-block pipelining).
// mode 0: qkv-scatter epilogue (reference's 192-channel head rule);
// mode 2: proj out f32, float4 store. bias: gcol<512?bias0:bias1 (kv merge).
#define BM 128
#define BN 64
#define QSCALE 0.18033688f   /* 0.125 * log2(e) */
__global__ __launch_bounds__(256) void gemm_kernel(
    const u16* __restrict__ A, int lda,
    const u16* __restrict__ Bt, int ldb,
    const float* __restrict__ bias0, const float* __restrict__ bias1,
    int K, int mode, int coff,
    u16* __restrict__ oq, u16* __restrict__ ok, u16* __restrict__ ov,
    float* __restrict__ out32)
{
    __shared__ __align__(16) u16 As[BM * 64];
    __shared__ __align__(16) u16 Bs[BN * 64];
    const int tid = threadIdx.x;
    const int lane = tid & 63, w = tid >> 6;
    const int row0 = blockIdx.x * BM, col0 = blockIdx.y * BN;
    const int woffM = (w & 1) * 64, woffN = (w >> 1) * 32;
    const int lr = lane & 15, kg = lane >> 4;
    f32x4 acc[4][2] = {};
    int k0 = 0;
    for (; k0 + 64 <= K; k0 += 64) {
#pragma unroll
        for (int h = 0; h < 6; ++h) {
            int c = tid + h * 256;
            if (c < 1024) {                // A: 128 rows x 8 slots
                int r = c >> 3, sl = c & 7;
                int kc = sl ^ (r & 7);     // source-side xor swizzle
                __builtin_amdgcn_global_load_lds(
                    (AS1C)(A + (size_t)(row0 + r) * lda + k0 + kc * 8),
                    (AS3)(As + c * 8), 16, 0, 0);
            } else {                       // B: 64 rows x 8 slots
                int cB = c - 1024;
                int r = cB >> 3, sl = cB & 7;
                int kc = sl ^ (r & 7);
                __builtin_amdgcn_global_load_lds(
                    (AS1C)(Bt + (size_t)(col0 + r) * ldb + k0 + kc * 8),
                    (AS3)(Bs + cB * 8), 16, 0, 0);
            }
        }
        __syncthreads();
        short8 af[4][2], bfr[2][2];
#pragma unroll
        for (int m = 0; m < 4; ++m) {
            int r = woffM + m * 16 + lr;
            const u16* base = As + r * 64;
            af[m][0] = *(const short8*)(base + ((kg ^ (r & 7)) * 8));
            af[m][1] = *(const short8*)(base + (((kg + 4) ^ (r & 7)) * 8));
        }
#pragma unroll
        for (int n = 0; n < 2; ++n) {
            int r = woffN + n * 16 + lr;
            const u16* base = Bs + r * 64;
            bfr[n][0] = *(const short8*)(base + ((kg ^ (r & 7)) * 8));
            bfr[n][1] = *(const short8*)(base + (((kg + 4) ^ (r & 7)) * 8));
        }
#pragma unroll
        for (int m = 0; m < 4; ++m)
#pragma unroll
            for (int n = 0; n < 2; ++n) {
                acc[m][n] = __builtin_amdgcn_mfma_f32_16x16x32_bf16(af[m][0], bfr[n][0], acc[m][n], 0, 0, 0);
                acc[m][n] = __builtin_amdgcn_mfma_f32_16x16x32_bf16(af[m][1], bfr[n][1], acc[m][n], 0, 0, 0);
            }
        __syncthreads();
    }
    if (k0 < K) {   // 32-wide tail (K=544): round-12-style staging, stride 32
#pragma unroll
        for (int h = 0; h < 3; ++h) {
            int c = tid + h * 256;
            if (c < 512) {                 // A: 128 rows x 4 slots
                int r = c >> 2, sl = c & 3;
                int kc = sl ^ (r & 3);
                __builtin_amdgcn_global_load_lds(
                    (AS1C)(A + (size_t)(row0 + r) * lda + k0 + kc * 8),
                    (AS3)(As + c * 8), 16, 0, 0);
            } else {                       // B: 64 rows x 4 slots
                int cB = c - 512;
                int r = cB >> 2, sl = cB & 3;
                int kc = sl ^ (r & 3);
                __builtin_amdgcn_global_load_lds(
                    (AS1C)(Bt + (size_t)(col0 + r) * ldb + k0 + kc * 8),
                    (AS3)(Bs + cB * 8), 16, 0, 0);
            }
        }
        __syncthreads();
        short8 af[4], bfr[2];
#pragma unroll
        for (int m = 0; m < 4; ++m) {
            int r = woffM + m * 16 + lr;
            af[m] = *(const short8*)(As + r * 32 + ((kg ^ (r & 3)) * 8));
        }
#pragma unroll
        for (int n = 0; n < 2; ++n) {
            int r = woffN + n * 16 + lr;
            bfr[n] = *(const short8*)(Bs + r * 32 + ((kg ^ (r & 3)) * 8));
        }
#pragma unroll
        for (int m = 0; m < 4; ++m)
#pragma unroll
            for (int n = 0; n < 2; ++n)
                acc[m][n] = __builtin_amdgcn_mfma_f32_16x16x32_bf16(af[m], bfr[n], acc[m][n], 0, 0, 0);
        __syncthreads();
    }
#pragma unroll
    for (int m = 0; m < 4; ++m) {
#pragma unroll
        for (int n = 0; n < 2; ++n) {
            int gcol = col0 + woffN + n * 16 + lr;
            float bv = (gcol < 512) ? bias0[gcol] : bias1[gcol - 512];
            int growb = row0 + woffM + m * 16 + kg * 4;   // j=0..3 contiguous
            int bb = growb >> 10, t0v = growb & 1023;
            float v0 = acc[m][n][0] + bv, v1 = acc[m][n][1] + bv;
            float v2 = acc[m][n][2] + bv, v3 = acc[m][n][3] + bv;
            if (mode == 0) {
                int cg = coff + gcol;
                int h = cg / 192;
                int rr = cg - h * 192;
                int role = rr >> 6, d = rr & 63;
                if (role == 0) { v0 *= QSCALE; v1 *= QSCALE; v2 *= QSCALE; v3 *= QSCALE; }
                if (role == 2) {
                    size_t base = ((((size_t)bb * 8 + h) * 64 + d) << 10) + t0v;
                    u64 pk = (u64)f2bf(v0) | ((u64)f2bf(v1) << 16)
                           | ((u64)f2bf(v2) << 32) | ((u64)f2bf(v3) << 48);
                    *(u64*)(ov + base) = pk;
                } else {
                    u16* o = role ? ok : oq;
                    size_t base = ((((size_t)bb * 8 + h) * 1024 + t0v) << 6) + d;
                    o[base]       = f2bf(v0);
                    o[base + 64]  = f2bf(v1);
                    o[base + 128] = f2bf(v2);
                    o[base + 192] = f2bf(v3);
                }
            } else {
                size_t base = (((size_t)bb * 512 + gcol) << 10) + t0v;
                float4 f4; f4.x = v0; f4.y = v1; f4.z = v2; f4.w = v3;
                *(float4*)(out32 + base) = f4;
            }
        }
    }
}

// ---------------------------------------------------------------------------
// flash attention, swapped-QK^T, no-max softmax (exact by shift-invariance).
// LDS-staged K/V via global_load_lds (round-10: 122 -> 44 us). Round-12 PV:
// 2x mfma_16x16x16 per st-block, P consumed in-lane (no ds_bpermute).
// Round-16: P-pack + O-write via __float2bfloat16 HW casts (RNE; m240:
// compiler can fuse cast pairs to v_cvt_pk_bf16_f32 -- unlike hand-rolled
// f2bf bit math which defeats recognition). ~25% of attn VALU was pack cost.
__global__ __launch_bounds__(256, 1) void attn_kernel(
    const u16* __restrict__ qb, const u16* __restrict__ kb,
    const u16* __restrict__ vt, u16* __restrict__ ob)
{
    __shared__ __align__(16) u16 Kl[2][4096];   // [buf][64 rows x 8 chunks x 8 u16]
    __shared__ __align__(16) u16 Vl[2][4096];
    int tid = threadIdx.x, lane = tid & 63, w = tid >> 6;
    int bid = blockIdx.x;                       // 0..1023 flat
    int wid = (bid & 7) * 128 + (bid >> 3);     // XCD-contiguous work id
    int qt = wid & 15;
    int hh = (wid >> 4) & 7;
    int bbb = wid >> 7;
    int bh = bbb * 8 + hh;
    int q0 = qt * 64 + w * 16;
    int lr = lane & 15, kg = lane >> 4;
    const u16* qbase = qb + ((size_t)bh * 1024 + q0 + lr) * 64;
    short8 qf0 = *(const short8*)(qbase + kg * 8);
    short8 qf1 = *(const short8*)(qbase + 32 + kg * 8);
    f32x4 oT[4] = {};
    float lsum = 0.f;
    const u16* kbase = kb + (size_t)bh * 1024 * 64;
    const u16* vbase = vt + (size_t)bh * 64 * 1024;
    const int xr = lr & 7;
    const int vho = (kg & 1) * 4;     // within-chunk u16 offset for V b64 reads
    const int vkg2 = kg >> 1;

#define STAGE(bf, s0) { \
    int g0 = tid, g1 = tid + 256; \
    { int r = g0 >> 3, cl = g0 & 7, cg = cl ^ (r & 7); \
      __builtin_amdgcn_global_load_lds((AS1C)(kbase + (size_t)((s0) + r) * 64 + cg * 8), \
                                       (AS3)(&Kl[bf][g0 * 8]), 16, 0, 0); } \
    { int r = g1 >> 3, cl = g1 & 7, cg = cl ^ (r & 7); \
      __builtin_amdgcn_global_load_lds((AS1C)(kbase + (size_t)((s0) + r) * 64 + cg * 8), \
                                       (AS3)(&Kl[bf][g1 * 8]), 16, 0, 0); } \
    { int d = g0 >> 3, cl = g0 & 7, cg = cl ^ (d & 7); \
      __builtin_amdgcn_global_load_lds((AS1C)(vbase + (size_t)d * 1024 + (s0) + cg * 8), \
                                       (AS3)(&Vl[bf][g0 * 8]), 16, 0, 0); } \
    { int d = g1 >> 3, cl = g1 & 7, cg = cl ^ (d & 7); \
      __builtin_amdgcn_global_load_lds((AS1C)(vbase + (size_t)d * 1024 + (s0) + cg * 8), \
                                       (AS3)(&Vl[bf][g1 * 8]), 16, 0, 0); } }

#define BODY(bf, st2) { \
    const u16* Kb = &Kl[bf][0]; \
    const u16* Vb = &Vl[bf][0]; \
    int rA = ((st2) * 32 + lr) * 64, rB = ((st2) * 32 + 16 + lr) * 64; \
    short8 k00 = *(const short8*)(Kb + rA + ((kg ^ xr) * 8)); \
    short8 k01 = *(const short8*)(Kb + rA + (((kg + 4) ^ xr) * 8)); \
    short8 k10 = *(const short8*)(Kb + rB + ((kg ^ xr) * 8)); \
    short8 k11 = *(const short8*)(Kb + rB + (((kg + 4) ^ xr) * 8)); \
    f32x4 sc0 = {}, sc1 = {}; \
    sc0 = __builtin_amdgcn_mfma_f32_16x16x32_bf16(k00, qf0, sc0, 0, 0, 0); \
    sc0 = __builtin_amdgcn_mfma_f32_16x16x32_bf16(k01, qf1, sc0, 0, 0, 0); \
    sc1 = __builtin_amdgcn_mfma_f32_16x16x32_bf16(k10, qf0, sc1, 0, 0, 0); \
    sc1 = __builtin_amdgcn_mfma_f32_16x16x32_bf16(k11, qf1, sc1, 0, 0, 0); \
    float p0 = fast_exp2(sc0[0]), p1 = fast_exp2(sc0[1]); \
    float p2 = fast_exp2(sc0[2]), p3 = fast_exp2(sc0[3]); \
    float p4 = fast_exp2(sc1[0]), p5 = fast_exp2(sc1[1]); \
    float p6 = fast_exp2(sc1[2]), p7 = fast_exp2(sc1[3]); \
    lsum += (((p0 + p1) + (p2 + p3)) + ((p4 + p5) + (p6 + p7))); \
    union { short4v s4; u32 u[2]; } pb0u, pb1u; \
    pb0u.u[0] = pkbf(p0, p1);  pb0u.u[1] = pkbf(p2, p3); \
    pb1u.u[0] = pkbf(p4, p5);  pb1u.u[1] = pkbf(p6, p7); \
    int c0 = ((((st2) * 4 + vkg2) ^ xr) * 8) + vho; \
    int c1 = ((((st2) * 4 + 2 + vkg2) ^ xr) * 8) + vho; \
    short4v va; \
    va = *(const short4v*)(Vb + (lr) * 64 + c0);       oT[0] = mfma16(va, pb0u.s4, oT[0]); \
    va = *(const short4v*)(Vb + (lr) * 64 + c1);       oT[0] = mfma16(va, pb1u.s4, oT[0]); \
    va = *(const short4v*)(Vb + (16 + lr) * 64 + c0);  oT[1] = mfma16(va, pb0u.s4, oT[1]); \
    va = *(const short4v*)(Vb + (16 + lr) * 64 + c1);  oT[1] = mfma16(va, pb1u.s4, oT[1]); \
    va = *(const short4v*)(Vb + (32 + lr) * 64 + c0);  oT[2] = mfma16(va, pb0u.s4, oT[2]); \
    va = *(const short4v*)(Vb + (32 + lr) * 64 + c1);  oT[2] = mfma16(va, pb1u.s4, oT[2]); \
    va = *(const short4v*)(Vb + (48 + lr) * 64 + c0);  oT[3] = mfma16(va, pb0u.s4, oT[3]); \
    va = *(const short4v*)(Vb + (48 + lr) * 64 + c1);  oT[3] = mfma16(va, pb1u.s4, oT[3]); }

    STAGE(0, 0)
    __syncthreads();               // barrier drains vmcnt -> buf0 ready
    for (int step = 0; step < 16; ++step) {
        int cur = step & 1;
        if (step < 15) STAGE(cur ^ 1, (step + 1) * 64)   // prefetch next tile
        BODY(cur, 0)
        BODY(cur, 1)
        __syncthreads();           // drains prefetch vmcnt + guards reuse
    }
#undef STAGE
#undef BODY

    float Z = lsum;
    Z += __shfl_xor(Z, 16);
    Z += __shfl_xor(Z, 32);
    float inv = 1.f / Z;
    u16* obase = ob + ((size_t)bbb * 1024 + q0 + lr) * 512 + hh * 64;
#pragma unroll
    for (int dt = 0; dt < 4; ++dt) {
        u32 lo = pkbf(oT[dt][0] * inv, oT[dt][1] * inv);
        u32 hi = pkbf(oT[dt][2] * inv, oT[dt][3] * inv);
        u32* dstp = (u32*)(obase + dt * 16 + kg * 4);
        dstp[0] = lo; dstp[1] = hi;
    }
}

// ---------------------------------------------------------------------------
extern "C" void kernel_launch(void* const* d_in, const int* in_sizes, int n_in,
                              void* d_out, int out_size, void* d_ws, size_t ws_size,
                              hipStream_t stream)
{
    (void)in_sizes; (void)n_in; (void)out_size;
    const float* x       = (const float*)d_in[0];
    const float* pose    = (const float*)d_in[1];
    const float* norm_g  = (const float*)d_in[2];
    const float* norm_b  = (const float*)d_in[3];
    const float* pnorm_g = (const float*)d_in[4];
    const float* pnorm_b = (const float*)d_in[5];
    const float* pose_W  = (const float*)d_in[6];
    const float* pose_b  = (const float*)d_in[7];
    const float* q_W     = (const float*)d_in[8];
    const float* q_b     = (const float*)d_in[9];
    const float* k_W     = (const float*)d_in[10];
    const float* k_b     = (const float*)d_in[11];
    const float* v_W     = (const float*)d_in[12];
    const float* v_b     = (const float*)d_in[13];
    const float* proj_W  = (const float*)d_in[14];
    const float* proj_b  = (const float*)d_in[15];
    float* out = (float*)d_out;

    if (ws_size < 44695552u) return;

    char* ws = (char*)d_ws;
    float* pe_ws = (float*)(ws);                       // 65,536 B
    u16* xn    = (u16*)(ws + 65536);                   // 8,388,608 (reused as obuf)
    u16* xpn   = (u16*)(ws + 8454144);                 // 8,912,896
    u16* qWt   = (u16*)(ws + 17367040);                // 524,288
    u16* kWt   = (u16*)(ws + 17891328);                // 557,056  (kv merged:
    u16* vWt   = (u16*)(ws + 18448384);                //  vWt adjacent to kWt)
    u16* pWt   = (u16*)(ws + 19005440);                // 524,288
    u16* qbuf  = (u16*)(ws + 19529728);                // 8,388,608
    u16* kbuf  = (u16*)(ws + 27918336);                // 8,388,608
    u16* vtb   = (u16*)(ws + 36306944);                // 8,388,608
    u16* obuf  = xn;  // xn dead after q-gemm; attn writes obuf afterwards

    hipLaunchKernelGGL(wtrans_kernel, dim3(16, 17, 4), dim3(256), 0, stream,
                       q_W, k_W, v_W, proj_W, qWt, kWt, vWt, pWt);
    hipLaunchKernelGGL(pe_kernel, dim3(16), dim3(256), 0, stream,
                       pose, pose_W, pose_b, pe_ws);
    hipLaunchKernelGGL(lnpack_kernel, dim3(32, 8), dim3(512), 0, stream,
                       x, pe_ws, norm_g, norm_b, pnorm_g, pnorm_b, xn, xpn);
    // q projection (concat channels 0..511)
    hipLaunchKernelGGL(gemm_kernel, dim3(64, 8), dim3(256), 0, stream,
                       xn, 512, qWt, 512, q_b, q_b, 512, 0, 0,
                       qbuf, kbuf, vtb, (float*)nullptr);
    // merged k+v projection (concat channels 512..1535; kWt/vWt adjacent)
    hipLaunchKernelGGL(gemm_kernel, dim3(64, 16), dim3(256), 0, stream,
                       xpn, 544, kWt, 544, k_b, v_b, 544, 0, 512,
                       qbuf, kbuf, vtb, (float*)nullptr);
    hipLaunchKernelGGL(attn_kernel, dim3(1024), dim3(256), 0, stream,
                       qbuf, kbuf, vtb, obuf);
    hipLaunchKernelGGL(gemm_kernel, dim3(64, 8), dim3(256), 0, stream,
                       obuf, 512, pWt, 512, proj_b, proj_b, 512, 2, 0,
                       (u16*)nullptr, (u16*)nullptr, (u16*)nullptr, out);
}